// Round 1
// baseline (1485.538 us; speedup 1.0000x reference)
//
#include <hip/hip_runtime.h>

#define FEAT 256
#define BAG  128
#define MT   128      // items per block
#define KC   64       // K chunk
#define XSTR 72       // LDS row stride in bf16 (64 + 8 pad -> 2-way bank alias, free)
#define HSTR 136      // epilogue LDS stride (128 + 8 pad)
#define EPS  1e-5f

typedef __bf16 bf16_t;
typedef __attribute__((ext_vector_type(8))) bf16_t bf16x8;
typedef __attribute__((ext_vector_type(4))) float f32x4;

__device__ __forceinline__ unsigned short f2bf(float f) {
  unsigned int u = __float_as_uint(f);
  u += 0x7FFFu + ((u >> 16) & 1u);   // RNE
  return (unsigned short)(u >> 16);
}
__device__ __forceinline__ float bf2f(unsigned short h) {
  return __uint_as_float(((unsigned int)h) << 16);
}

// ---- W fp32 -> bf16 (32768 elems, grid 32x256) ----
__global__ void conv_w_kernel(const float* __restrict__ W,
                              unsigned short* __restrict__ Wb) {
  int i = (blockIdx.x * 256 + threadIdx.x) * 4;
  float4 v = *(const float4*)(W + i);
  ushort4 o;
  o.x = f2bf(v.x); o.y = f2bf(v.y); o.z = f2bf(v.z); o.w = f2bf(v.w);
  *(ushort4*)(Wb + i) = o;
}

// ---- fused GEMM(relu) + segment-sum ----
__global__ __launch_bounds__(256, 4) void fused_gemm_seg(
    const float* __restrict__ x, const unsigned short* __restrict__ Wb,
    const float* __restrict__ b, const int* __restrict__ seg_ids,
    float* __restrict__ agg, int n_items)
{
  __shared__ __align__(16) unsigned short smem[MT * XSTR * 2]; // 36864 B
  __shared__ int   segs[MT];
  __shared__ float bsm[BAG];
  unsigned short* Xs  = smem;              // [128][72]
  unsigned short* Wsm = smem + MT * XSTR;  // [128][72]
  unsigned short* Hs  = smem;              // reuse: [128][136] bf16 (34816 B)

  const int t = threadIdx.x;
  const int item0 = blockIdx.x * MT;

  if (t < MT) {
    int it = item0 + t;
    segs[t] = (it < n_items) ? seg_ids[it] : -1;
  } else {
    bsm[t - MT] = b[t - MT];
  }

  const int lane = t & 63;
  const int wave = t >> 6;
  const int quad = lane >> 4;
  const int l16  = lane & 15;
  const int row_off = (wave >> 1) * 64;   // wave tile: 64x64
  const int col_off = (wave & 1)  * 64;

  f32x4 acc[4][4] = {};

  const int col4 = t & 15;   // x staging: 16 float4 per row-chunk
  const int rowi = t >> 4;   // 16 rows per pass
  const int u8c  = t & 7;    // W staging: 8 x ushort8 per row-chunk
  const int rw   = t >> 3;   // 32 rows per pass

  for (int kc = 0; kc < FEAT; kc += KC) {
    __syncthreads();
    // stage x[item0..+127][kc..+63] fp32 -> bf16 LDS
    #pragma unroll
    for (int i = 0; i < 8; i++) {
      int row = rowi + i * 16;
      int it = item0 + row;
      float4 v = make_float4(0.f, 0.f, 0.f, 0.f);
      if (it < n_items) v = *(const float4*)(x + (long)it * FEAT + kc + col4 * 4);
      ushort4 o;
      o.x = f2bf(v.x); o.y = f2bf(v.y); o.z = f2bf(v.z); o.w = f2bf(v.w);
      *(ushort4*)(Xs + row * XSTR + col4 * 4) = o;
    }
    // stage Wb[0..127][kc..+63] bf16 -> LDS
    #pragma unroll
    for (int i = 0; i < 4; i++) {
      int row = rw + i * 32;
      int4 v = *(const int4*)(Wb + row * FEAT + kc + u8c * 8);
      *(int4*)(Wsm + row * XSTR + u8c * 8) = v;
    }
    __syncthreads();
    // 2 K-steps of 32
    #pragma unroll
    for (int ks = 0; ks < KC; ks += 32) {
      int kb = ks + quad * 8;
      bf16x8 af[4], bfr[4];
      #pragma unroll
      for (int i = 0; i < 4; i++)
        af[i] = *(const bf16x8*)(Xs + (row_off + i * 16 + l16) * XSTR + kb);
      #pragma unroll
      for (int j = 0; j < 4; j++)
        bfr[j] = *(const bf16x8*)(Wsm + (col_off + j * 16 + l16) * XSTR + kb);
      #pragma unroll
      for (int i = 0; i < 4; i++)
        #pragma unroll
        for (int j = 0; j < 4; j++)
          acc[i][j] = __builtin_amdgcn_mfma_f32_16x16x32_bf16(af[i], bfr[j], acc[i][j], 0, 0, 0);
    }
  }

  __syncthreads();  // done with Xs/Wsm; reuse as Hs

  float bcol[4];
  #pragma unroll
  for (int j = 0; j < 4; j++) bcol[j] = bsm[col_off + j * 16 + l16];

  // epilogue: +b, relu, store bf16 to LDS (C layout: col=lane&15, row=quad*4+reg)
  #pragma unroll
  for (int i = 0; i < 4; i++) {
    int rbase = row_off + i * 16 + quad * 4;
    #pragma unroll
    for (int j = 0; j < 4; j++) {
      int c = col_off + j * 16 + l16;
      #pragma unroll
      for (int r = 0; r < 4; r++) {
        float v = acc[i][j][r] + bcol[j];
        v = v > 0.f ? v : 0.f;
        Hs[(rbase + r) * HSTR + c] = f2bf(v);
      }
    }
  }
  __syncthreads();

  // per-column segment-run reduction (seg_ids sorted); branches are wave-uniform
  {
    const int c  = t & 127;
    const int r0 = (t >> 7) * 64;
    float s = 0.f;
    int cur = -1;
    for (int r = r0; r < r0 + 64; r++) {
      int sg = segs[r];
      if (sg < 0) break;                 // tail rows only
      if (sg != cur) {
        if (cur >= 0) atomicAdd(agg + (long)cur * BAG + c, s);
        cur = sg; s = 0.f;
      }
      s += bf2f(Hs[r * HSTR + c]);
    }
    if (cur >= 0) atomicAdd(agg + (long)cur * BAG + c, s);
  }
}

// ---- agg = sums / max(cnt,1), accumulate per-feature sum/sumsq ----
__global__ __launch_bounds__(256) void bag_stats_kernel(
    float* __restrict__ agg, const int* __restrict__ bags_len,
    float* __restrict__ fsum, float* __restrict__ fsq, int nbags)
{
  const int f = threadIdx.x & 127;
  const int g = threadIdx.x >> 7;
  const int bag0 = blockIdx.x * 128;
  float s = 0.f, q = 0.f;
  for (int i = 0; i < 64; i++) {
    int bag = bag0 + g + 2 * i;
    if (bag < nbags) {
      int c = bags_len[bag]; if (c < 1) c = 1;
      long idx = (long)bag * BAG + f;
      float v = agg[idx] / (float)c;
      agg[idx] = v;
      s += v; q += v * v;
    }
  }
  __shared__ float ls[256], lq[256];
  ls[threadIdx.x] = s; lq[threadIdx.x] = q;
  __syncthreads();
  if (threadIdx.x < 128) {
    s = ls[threadIdx.x] + ls[threadIdx.x + 128];
    q = lq[threadIdx.x] + lq[threadIdx.x + 128];
    atomicAdd(fsum + f, s);
    atomicAdd(fsq + f, q);
  }
}

// ---- scale/shift from batch stats (1 block x 128) ----
__global__ void mk_scale_kernel(const float* __restrict__ fsum, const float* __restrict__ fsq,
                                const float* __restrict__ gamma, const float* __restrict__ beta,
                                float* __restrict__ scale, float* __restrict__ shift, int nbags)
{
  int f = threadIdx.x;
  float inv_n = 1.f / (float)nbags;
  float mean = fsum[f] * inv_n;
  float var  = fsq[f] * inv_n - mean * mean;
  float sc = gamma[f] * rsqrtf(var + EPS);
  scale[f] = sc;
  shift[f] = beta[f] - mean * sc;
}

// ---- normalize in place: out = agg*scale[f] + shift[f] ----
__global__ __launch_bounds__(256) void norm_out_kernel(
    float* __restrict__ out, const float* __restrict__ scale,
    const float* __restrict__ shift, long n4)
{
  long i = (long)blockIdx.x * 256 + threadIdx.x;
  if (i >= n4) return;
  long base = i * 4;
  int f0 = (int)(base & 127);
  float4 v  = *(const float4*)(out + base);
  float4 sc = *(const float4*)(scale + f0);
  float4 sh = *(const float4*)(shift + f0);
  v.x = v.x * sc.x + sh.x;
  v.y = v.y * sc.y + sh.y;
  v.z = v.z * sc.z + sh.z;
  v.w = v.w * sc.w + sh.w;
  *(float4*)(out + base) = v;
}

extern "C" void kernel_launch(void* const* d_in, const int* in_sizes, int n_in,
                              void* d_out, int out_size, void* d_ws, size_t ws_size,
                              hipStream_t stream) {
  const float* x     = (const float*)d_in[0];
  const float* W     = (const float*)d_in[1];
  const float* b     = (const float*)d_in[2];
  const float* gamma = (const float*)d_in[3];
  const float* beta  = (const float*)d_in[4];
  const int* seg     = (const int*)d_in[5];
  const int* blen    = (const int*)d_in[6];
  float* out = (float*)d_out;

  const int n_items = in_sizes[0] / FEAT;   // 1,000,000
  const int nbags   = in_sizes[6];          // 50,000

  char* ws = (char*)d_ws;
  float* fsum          = (float*)(ws);            // 512 B
  float* fsq           = (float*)(ws + 512);      // 512 B
  unsigned short* Wb   = (unsigned short*)(ws + 1024);   // 65536 B
  float* scale         = (float*)(ws + 66560);    // 512 B
  float* shift         = (float*)(ws + 67072);    // 512 B

  // d_out doubles as the segment-sum / agg buffer (exactly nbags*BAG floats)
  hipMemsetAsync(d_out, 0, (size_t)out_size * sizeof(float), stream);
  hipMemsetAsync(ws, 0, 1024, stream);

  conv_w_kernel<<<(BAG * FEAT / 4 + 255) / 256, 256, 0, stream>>>(W, Wb);

  int gblocks = (n_items + MT - 1) / MT;
  fused_gemm_seg<<<gblocks, 256, 0, stream>>>(x, Wb, b, seg, out, n_items);

  int sblocks = (nbags + 127) / 128;
  bag_stats_kernel<<<sblocks, 256, 0, stream>>>(out, blen, fsum, fsq, nbags);

  mk_scale_kernel<<<1, 128, 0, stream>>>(fsum, fsq, gamma, beta, scale, shift, nbags);

  long n4 = (long)out_size / 4;
  norm_out_kernel<<<(int)((n4 + 255) / 256), 256, 0, stream>>>(out, scale, shift, n4);
}